// Round 2
// baseline (685.930 us; speedup 1.0000x reference)
//
#include <hip/hip_runtime.h>

#define BB 64
#define TT 1024
#define CC 2
#define NN 128

#define REP16(M) M(0)M(1)M(2)M(3)M(4)M(5)M(6)M(7)M(8)M(9)M(10)M(11)M(12)M(13)M(14)M(15)

// fp32 -> bf16 bits, round-to-nearest-even (inputs are never NaN here)
static __device__ __forceinline__ unsigned f2bf(float x) {
    const unsigned u = __float_as_uint(x);
    return (u + 0x7FFFu + ((u >> 16) & 1u)) >> 16;
}
static __device__ __forceinline__ unsigned pk2(float lo, float hi) {
    return f2bf(lo) | (f2bf(hi) << 16);
}

// D.f32 += S0.bf16[0]*S1.bf16[0] + S0.bf16[1]*S1.bf16[1]  (VOP3P, full rate)
#define DOT(acc, pp, ee) \
    asm("v_dot2_f32_bf16 %0, %1, %2, %0" : "+v"(acc) : "v"(pp), "v"(ee));

// Per chunk c (rows 8c..8c+7): one b128 broadcast read of p-pairs + one
// swizzled b128 read of this thread's E-column pairs + 4 dot2.
// E read: offset = eoff0 ^ (c<<4); eoff0 bits 4..7 hold (j&15), so the XOR
// stays inside row j (16B-block swizzle, write side uses the same XOR).
#define MV(c) { const uint4 q = pb[c]; \
    const uint4 e = *(const uint4*)(Elb + (eoff0 ^ ((c) << 4))); \
    DOT(a0, q.x, e.x) DOT(a1, q.y, e.y) \
    DOT(a2, q.z, e.z) DOT(a3, q.w, e.w) }

// Raw workgroup barrier: producer-visibility via lgkmcnt(0) ONLY (global
// prefetch loads stay in flight across the barrier). WAR safety on the
// double-buffered p: each wave's lgkmcnt(0) at the NEXT barrier drains its
// reads before any wave re-writes that buffer two iterations later.
static __device__ __forceinline__ void wg_barrier() {
    asm volatile("s_waitcnt lgkmcnt(0)" ::: "memory");
    __builtin_amdgcn_s_barrier();
    asm volatile("" ::: "memory");
}

// One workgroup (128 thr = 2 waves) per (b,c) chain; thread j owns tag j.
//
// ROUND-2 CHANGE: exp(E) column j now lives in LDS (row j, 64 packed-bf16
// u32 words, 16B-block XOR swizzle blk^=(j&15)), NOT in "pinned" VGPRs.
// Rocprof showed VGPR_Count=44-48 for the register-E kernel: the allocator
// never kept the 64 E registers resident — it spilled them to scratch, and
// every step paid ~16 hidden scratch b128 reloads at L2 latency inside the
// dot phase (invisible in FETCH_SIZE, low VALUBusy, ~700 stall cyc/step).
// LDS residency is allocator-proof; the 16 E b128 reads/step pipeline at
// ~12 cyc each alongside the p-broadcast reads and the dot chain.
//
// Critical-path factoring (kept from round 1): alpha_t = S_t + log(s_t) + e_t,
//   p_{t+1} = exp(alpha_t - S_{t+1}) = s_t * exp(S_t + e_t - S_{t+1})
// so __expf/__logf run off the serial chain (log only on thread 0's
// shift side-path, which has a full step of slack).
__global__ __launch_bounds__(128, 1) __attribute__((amdgpu_waves_per_eu(1, 1)))
void crf_logz_kernel(const float* __restrict__ emissions,
                     const int* __restrict__ lengths,
                     const float* __restrict__ transitions,
                     const float* __restrict__ start_trans,
                     const float* __restrict__ end_trans,
                     float* __restrict__ out)
{
    const int bc = blockIdx.x;
    const int b  = bc >> 1;
    const int c  = bc & 1;
    const int j  = threadIdx.x;            // 0..127, owns tag j
    const int jl = j & 15;

    __shared__ __align__(16) unsigned El[NN][64];          // 32KB: packed exp(E) columns
    __shared__ __align__(16) unsigned short pbufs[2][NN];  // bf16 p, double-buffered
    __shared__ float shbuf[2];             // shift broadcast (alpha_t[0]), parity-buffered
    __shared__ float red[NN];              // final reduction scratch

    const float* tr = transitions + c * NN * NN;

    // Setup: thread j packs exp of E-column j into LDS row j with the
    // 16B-block swizzle: logical word i -> phys word ((i>>2)^jl)<<2 | (i&3).
    #pragma unroll 4
    for (int i = 0; i < 64; ++i) {
        const unsigned v = pk2(__expf(tr[(2 * i) * NN + j]),
                               __expf(tr[(2 * i + 1) * NN + j]));
        El[j][((((i >> 2)) ^ jl) << 2) | (i & 3)] = v;
    }

    const char* Elb = (const char*)El;
    const unsigned eoff0 = j * 256 + (jl << 4);   // row base + swizzle seed

    const int len  = lengths[b];           // in [T/2, T]
    const int tmax = len - 1;

    // emissions[b][t][c][*]; t-stride = CC*NN floats; coalesced per wave
    const float* emisb = emissions + ((size_t)b * TT * CC + c) * NN;

    const float alpha0 = start_trans[c * NN + j] + emisb[j];  // alpha_0[j]
    if (j == 0) shbuf[0] = alpha0;         // S_2 = alpha_0[0]; visible after barrier t=1

    // p_1 = exp(alpha_0 - S_1) with S_1 = 0 (|alpha_0| < ~12)
    unsigned pbits = f2bf(__expf(alpha0));
    float Scur = 0.f;                      // S_t for t = 1

    // 2-deep register emission pipeline (stays in flight across raw barriers)
    const int t1 = (1 < tmax) ? 1 : tmax, t2 = (2 < tmax) ? 2 : tmax;
    float ecur = emisb[(size_t)t1 * (CC * NN) + j];   // e_t
    float enx  = emisb[(size_t)t2 * (CC * NN) + j];   // e_{t+1}

    float s = 0.f, Sfin = 0.f, efin = ecur;

    for (int t = 1; t < len; ++t) {
        pbufs[t & 1][j] = (unsigned short)pbits;   // p_t, packed last iteration
        wg_barrier();                              // lgkm-only: vmcnt stays in flight

        // prefetch emission for t+2 (clamped); never drained by the barrier
        const int tp = (t + 2 <= tmax) ? (t + 2) : tmax;
        const float el = emisb[(size_t)tp * (CC * NN) + j];

        const float Snxt = shbuf[(t - 1) & 1];     // S_{t+1} = alpha_{t-1}[0]
        const float f = __expf(Scur + ecur - Snxt); // || with dots (no dep on s)

        const uint4* __restrict__ pb = (const uint4*)pbufs[t & 1];
        float a0 = 0.f, a1 = 0.f, a2 = 0.f, a3 = 0.f;
        REP16(MV)                          // 16 p-broadcasts + 16 E-reads + 64 dot2
        s = (a0 + a1) + (a2 + a3);         // s_t[j]

        // S_{t+2} = alpha_t[0]; thread 0's log has a step of slack
        if (j == 0) shbuf[t & 1] = Scur + __logf(s) + ecur;

        pbits = f2bf(s * f);               // p_{t+1}[j] -> bf16 (critical: 1 mul + pack)

        Sfin = Scur; efin = ecur;          // snapshot for epilogue
        Scur = Snxt; ecur = enx; enx = el;
    }

    // alpha_{len-1}[j] = S_{len-1} + log(s_{len-1}[j]) + e_{len-1}[j]
    const float alpha = (tmax == 0) ? alpha0 : (Sfin + __logf(s) + efin);

    // final logsumexp over tags
    red[j] = alpha + end_trans[c * NN + j];
    __syncthreads();
    if (j < 64) {
        const float x = red[j], y = red[j + 64];
        float m = fmaxf(x, y);
        #pragma unroll
        for (int off = 32; off > 0; off >>= 1)
            m = fmaxf(m, __shfl_xor(m, off));
        float ssum = __expf(x - m) + __expf(y - m);
        #pragma unroll
        for (int off = 32; off > 0; off >>= 1)
            ssum += __shfl_xor(ssum, off);
        if (j == 0) out[b * CC + c] = m + __logf(ssum);
    }
}

extern "C" void kernel_launch(void* const* d_in, const int* in_sizes, int n_in,
                              void* d_out, int out_size, void* d_ws, size_t ws_size,
                              hipStream_t stream) {
    const float* emissions   = (const float*)d_in[0];
    const int*   lengths     = (const int*)d_in[1];
    const float* transitions = (const float*)d_in[2];
    const float* start_t     = (const float*)d_in[3];
    const float* end_t       = (const float*)d_in[4];
    float* out = (float*)d_out;

    crf_logz_kernel<<<BB * CC, NN, 0, stream>>>(
        emissions, lengths, transitions, start_t, end_t, out);
}